// Round 1
// 208.577 us; speedup vs baseline: 1.0500x; 1.0500x over previous
//
#include <hip/hip_runtime.h>

// CvT block, MI355X bf16-MFMA implementation.
// B=32, C=128, L=32 (seq=1024), H=8, DK=64, HD=512, NLAYER=4.
// R11: attn rework: (a) bias C-operands served from a 12-slot LDS ring
// (48KB) holding the sliding 9-dxx circulant window; only 2 new dxx
// (8KB/block) staged per key tile -> bias L2 loads (16/kt/wave) leave the
// critical path; (b) K/V staged with async global_load_lds (width 16),
// double-buffered, one barrier per tile; (c) per-qt fused S->exp->pack->O
// chain + s_setprio around MFMA clusters; (d) prep_wb/prep_xt merged.

#define NB   32
#define NH   8
#define SEQ  1024
#define DKH  64
#define HDIM 512
#define CIN  128

// 0.125 * log2(e): folded into Wq and bias so scores are in exp2 domain.
#define SCL 0.18033688011112042f

typedef __bf16 bf16x8 __attribute__((ext_vector_type(8)));
typedef float floatx4 __attribute__((ext_vector_type(4)));
typedef unsigned short u16x8 __attribute__((ext_vector_type(8)));
typedef unsigned int uintx4 __attribute__((ext_vector_type(4)));

__device__ __forceinline__ unsigned short f2bf(float f) {
    union { float f; unsigned int u; } c; c.f = f;
    unsigned int u = c.u;
    return (unsigned short)((u + 0x7fffu + ((u >> 16) & 1u)) >> 16); // RNE
}
__device__ __forceinline__ bf16x8 ldfrag(const unsigned short* p) {
    u16x8 v = *reinterpret_cast<const u16x8*>(p);
    return __builtin_bit_cast(bf16x8, v);
}
// pack two f32 -> two RNE bf16; 'a' lands in the LOW short.
__device__ __forceinline__ unsigned int pkbf(float a, float b) {
    unsigned int ua = __builtin_bit_cast(unsigned int, a);
    unsigned int ub = __builtin_bit_cast(unsigned int, b);
    ua += 0x7fffu + ((ua >> 16) & 1u);
    ub += 0x7fffu + ((ub >> 16) & 1u);
    return __builtin_amdgcn_perm(ub, ua, 0x07060302u);
}
// truncation pack (P>0): one v_perm, no rounding adds.
__device__ __forceinline__ unsigned int pkbf_t(float a, float b) {
    return __builtin_amdgcn_perm(__builtin_bit_cast(unsigned int, b),
                                 __builtin_bit_cast(unsigned int, a), 0x07060302u);
}
// async global->LDS, 16B per lane; LDS dest = wave-uniform base + lane*16.
__device__ __forceinline__ void g2l16(const void* g, void* l) {
    __builtin_amdgcn_global_load_lds((const __attribute__((address_space(1))) void*)g,
                                     (__attribute__((address_space(3))) void*)l, 16, 0, 0);
}

// Fragment-order storage: 512-elem block = one wave fragment [lane][j].
// Kf (A-frag, m=key): frag (s,c): lane (q,n) j <-> K[key=16s+n][d=32c+8q+j]
// Vf (A-frag, m=d, permuted k): frag (u,c): lane (q,n) jj <->
//     V[key = 32c+16(jj>>2)+4q+(jj&3)][d=16u+n]   (matches P^T pack order)

// ---------------- merged prep: bias + weight casts + x transpose ----------------
// blocks [0, 256): biasG f32 C-frag tiles, slot = ((h*32+dxx)*2+a)*2+bb:
//   biasG[slot*256 + lane*4 + r] = R[h][dxx][((a<<4)+n - (bb<<4)-4q-r)&31]*SCL
// blocks [256, 1280): weight casts; Wq scaled by SCL (exp2 domain).
// blocks [1280, 2304): xt2 = x transposed+scaled into B/A fragment order.
__global__ __launch_bounds__(256) void prep_all(const float* __restrict__ Wq,
                                                const float* __restrict__ Wk,
                                                const float* __restrict__ Wv,
                                                const float* __restrict__ W0,
                                                const float* __restrict__ R,
                                                const float* __restrict__ x,
                                                unsigned short* __restrict__ w2,
                                                unsigned short* __restrict__ w0f,
                                                float* __restrict__ biasG,
                                                unsigned short* __restrict__ xt2) {
    __shared__ float lds[64 * 65];
    int bid = blockIdx.x;
    if (bid < 256) {
        int gidx = bid * 256 + threadIdx.x;              // [0, 65536)
        int lane = gidx & 63, slot = gidx >> 6;          // slot in [0, 1024)
        int bb = slot & 1, a = (slot >> 1) & 1, dxx = (slot >> 2) & 31, h = slot >> 7;
        int q = lane >> 4, n = lane & 15;
        int iy = (a << 4) + n;
        const float* Rh = R + (h << 10) + (dxx << 5);
        floatx4 v;
        for (int r = 0; r < 4; ++r) {
            int jy = (bb << 4) + 4 * q + r;
            v[r] = Rh[(iy - jy) & 31] * SCL;
        }
        *(floatx4*)&biasG[(size_t)gidx * 4] = v;
    } else if (bid < 1280) {
        int idx = (bid - 256) * 256 + threadIdx.x;       // [0, 262144)
        if (idx < 196608) {
            int row = idx >> 7, col = idx & 127;
            float v;
            if (row < 512)       v = Wq[idx] * SCL;
            else if (row < 1024) v = Wk[idx - 65536];
            else                 v = Wv[idx - 131072];
            int rt = row >> 4, nr = row & 15, kc = col >> 5, qc = (col & 31) >> 3, jc = col & 7;
            w2[((rt * 4 + kc) * 512) + (qc * 16 + nr) * 8 + jc] = f2bf(v);
        } else {
            int idx2 = idx - 196608;
            int row = idx2 >> 9, col = idx2 & 511;
            int rt = row >> 4, nr = row & 15, kcA = col >> 5, qc = (col & 31) >> 3, jc = col & 7;
            w0f[((rt * 16 + kcA) * 512) + (qc * 16 + nr) * 8 + jc] = f2bf(W0[idx2]);
        }
    } else {
        int r = bid - 1280;                              // [0, 1024)
        int b = r & 31, yy = (r >> 5) & 1, zz = r >> 6;
        int c0 = yy * 64, p0 = zz * 64;
        int t = threadIdx.x, tr = t >> 6, tc = t & 63;
        const float inv_layer = 0.44721359549995793f;    // 1/sqrt(5)
        for (int rr = 0; rr < 16; ++rr) {
            int cl = rr * 4 + tr;
            lds[cl * 65 + tc] = x[(b * CIN + c0 + cl) * SEQ + p0 + tc];
        }
        __syncthreads();
        for (int rr = 0; rr < 16; ++rr) {
            int pl = rr * 4 + tr;
            int pos = p0 + pl, c = c0 + tc;
            int pt = pos >> 4, np = pos & 15, kc = c >> 5, qc = (c & 31) >> 3, jc = c & 7;
            xt2[((size_t)((b * 64 + pt) * 4 + kc) * 512) + (qc * 16 + np) * 8 + jc] =
                f2bf(lds[tc * 65 + pl] * inv_layer);
        }
    }
}

// ---------------- fused QKV projection ----------------
__global__ __launch_bounds__(256, 4) void qkv_gemm(const unsigned short* __restrict__ xt2,
                                                   const unsigned short* __restrict__ w2,
                                                   unsigned short* __restrict__ Qt,
                                                   unsigned short* __restrict__ Kf,
                                                   unsigned short* __restrict__ Vf) {
    int b = blockIdx.x, y = blockIdx.y, zt = blockIdx.z;
    int tid = threadIdx.x, wave = tid >> 6, lane = tid & 63, q = lane >> 4, n = lane & 15;
    floatx4 acc[4];
    for (int s = 0; s < 4; ++s) acc[s] = (floatx4){0.f, 0.f, 0.f, 0.f};
    bf16x8 af[4], bfr[4][4];
    if (y < 16) {
        int rt = y * 4 + wave;                       // wrow tile
        const unsigned short* wbase = w2 + (size_t)rt * 4 * 512 + lane * 8;
        const unsigned short* xbase = xt2 + (size_t)(b * 64 + zt * 4) * 4 * 512 + lane * 8;
        for (int kc = 0; kc < 4; ++kc) af[kc] = ldfrag(wbase + kc * 512);
        for (int s = 0; s < 4; ++s)
            for (int kc = 0; kc < 4; ++kc) bfr[s][kc] = ldfrag(xbase + (s * 4 + kc) * 512);
        for (int kc = 0; kc < 4; ++kc)
            for (int s = 0; s < 4; ++s)
                acc[s] = __builtin_amdgcn_mfma_f32_16x16x32_bf16(af[kc], bfr[s][kc], acc[s], 0, 0, 0);
        int wrow0 = y * 64 + wave * 16;
        int pos0 = zt * 64;
        if (y < 8) {
            int h = wrow0 >> 6;
            int d0 = (wrow0 & 63) + 4 * q;
            for (int s = 0; s < 4; ++s) {
                uint2 pk;
                pk.x = pkbf(acc[s][0], acc[s][1]);
                pk.y = pkbf(acc[s][2], acc[s][3]);
                int pos = pos0 + 16 * s + n;
                *(uint2*)&Qt[((size_t)(b * NH + h) * SEQ + pos) * DKH + d0] = pk;
            }
        } else {
            // K: d = wave*16+4q+r (regs), key = 16s+n. A-frag store.
            int h = (wrow0 >> 6) - 8;
            int bh = b * NH + h;
            int cd = wave >> 1;
            int qk = 2 * (wave & 1) + (q >> 1);
            int jk = 4 * (q & 1);
            for (int s = 0; s < 4; ++s) {
                uint2 pk;
                pk.x = pkbf(acc[s][0], acc[s][1]);
                pk.y = pkbf(acc[s][2], acc[s][3]);
                size_t addr = ((size_t)(bh * 16 + zt) * 8 + s * 2 + cd) * 512
                              + (qk * 16 + n) * 8 + jk;
                *(uint2*)&Kf[addr] = pk;
            }
        }
    } else {
        int pt = zt * 4 + wave;                      // pos tile
        const unsigned short* xbase = xt2 + (size_t)((b * 64 + pt) * 4) * 512 + lane * 8;
        int rtv0 = 64 + (y - 16) * 4;                // V wrow tiles start at row 1024
        const unsigned short* wbase = w2 + (size_t)rtv0 * 4 * 512 + lane * 8;
        for (int kc = 0; kc < 4; ++kc) af[kc] = ldfrag(xbase + kc * 512);
        for (int s = 0; s < 4; ++s)
            for (int kc = 0; kc < 4; ++kc) bfr[s][kc] = ldfrag(wbase + (s * 4 + kc) * 512);
        for (int kc = 0; kc < 4; ++kc)
            for (int s = 0; s < 4; ++s)
                acc[s] = __builtin_amdgcn_mfma_f32_16x16x32_bf16(af[kc], bfr[s][kc], acc[s], 0, 0, 0);
        // V: key = wave*16+4q+r (regs) -> Vf A-frag with PV k-permutation.
        int vrow0 = (y - 16) * 64;
        int cj = wave >> 1;
        int jj0 = 4 * (wave & 1);
        for (int s = 0; s < 4; ++s) {
            int vrow = vrow0 + 16 * s + n;
            int h = vrow >> 6, d = vrow & 63;
            int u = d >> 4, nl = d & 15;
            uint2 pk;
            pk.x = pkbf(acc[s][0], acc[s][1]);
            pk.y = pkbf(acc[s][2], acc[s][3]);
            size_t addr = ((size_t)((b * NH + h) * 16 + zt) * 8 + u * 2 + cj) * 512
                          + (q * 16 + nl) * 8 + jj0;
            *(uint2*)&Vf[addr] = pk;
        }
    }
}

// ---------------- attention (LDS bias ring + async staging) ----------------
// WG = 256 queries (4 waves x 64); key tiles of 64; one head per XCD.
// S^T = K Q^T with bias C-init read from a 12-slot LDS ring holding the
// sliding circulant window (9 dxx values live; 2 new staged per tile).
// K/V staged via global_load_lds double-buffer; ONE barrier per key tile.
__global__ __launch_bounds__(256, 2) void attn_kernel(const unsigned short* __restrict__ Qt,
                                                      const unsigned short* __restrict__ Kf,
                                                      const unsigned short* __restrict__ Vf,
                                                      const float* __restrict__ biasG,
                                                      unsigned short* __restrict__ att2) {
    __shared__ alignas(16) unsigned short lds_k[2][8 * 512];   // 16 KB
    __shared__ alignas(16) unsigned short lds_v[2][8 * 512];   // 16 KB
    __shared__ alignas(16) float lds_bias[12 * 1024];          // 48 KB ring

    int gid = blockIdx.x;
    int bh = gid & 255, qb = gid >> 8;
    int b = bh >> 3, h = bh & 7;
    int tid = threadIdx.x, wave = tid >> 6, lane = tid & 63, q = lane >> 4, n = lane & 15;
    int i0 = qb * 256 + wave * 64;
    int ti0 = i0 >> 4;

    const unsigned short* qbase = Qt + (size_t)bh * SEQ * DKH;
    const unsigned short* kft = Kf + (size_t)bh * 16 * 4096;
    const unsigned short* vft = Vf + (size_t)bh * 16 * 4096;
    const float* bGh = biasG + (size_t)h * 32768;   // per-head bias base (floats)

    // Q as B-fragments: lane (q,n): query = i0+16qt+n, d = c*32+8q+j
    bf16x8 aq[4][2];
    for (int qt = 0; qt < 4; ++qt)
        for (int c = 0; c < 2; ++c)
            aq[qt][c] = ldfrag(qbase + (i0 + 16 * qt + n) * DKH + c * 32 + q * 8);

    // all-ones A fragment for column-sum MFMA (l = 1^T P^T)
    u16x8 ones_u;
    for (int t = 0; t < 8; ++t) ones_u[t] = 0x3F80;
    bf16x8 vone = __builtin_bit_cast(bf16x8, ones_u);

    floatx4 o[4][4], acc_l[4];
    for (int qt = 0; qt < 4; ++qt) {
        acc_l[qt] = (floatx4){0.f, 0.f, 0.f, 0.f};
        for (int u = 0; u < 4; ++u) o[qt][u] = (floatx4){0.f, 0.f, 0.f, 0.f};
    }

    // Ring bookkeeping. raw dxx for (qt,s) at tile kt:
    //   raw = qb*8 + 2*wave + (qt>>1) - (s>>1) - 2*kt ; window = [wb, wb+8],
    //   wb = qb*8 - 1 - 2*kt. phys slot = (raw+48) % 12 (raw monotone -> safe).
    int wb64 = qb * 8 + 255;             // raw window base + 256 (for &31)
    int sbase = (qb * 8 + 47) % 12;      // phys slot of window base
    int abb = (wave >> 1) * 2 + (wave & 1);   // this wave's (a,bb) staging duty
    int off0 = wave * 512;               // wave chunk (shorts) for K/V staging

    // ---- prologue: stage full window(0) (9 dxx x 4 tiles) + K/V tile 0 ----
    {
        for (int rel = 0; rel < 9; ++rel) {
            int dxx = (wb64 + rel) & 31;
            int phys = sbase + rel; if (phys >= 12) phys -= 12;
            g2l16(bGh + (dxx * 4 + abb) * 256 + lane * 4,
                  &lds_bias[(phys * 4 + abb) * 256]);
        }
        g2l16(kft + off0 + lane * 8,        &lds_k[0][off0]);
        g2l16(kft + 2048 + off0 + lane * 8, &lds_k[0][2048 + off0]);
        g2l16(vft + off0 + lane * 8,        &lds_v[0][off0]);
        g2l16(vft + 2048 + off0 + lane * 8, &lds_v[0][2048 + off0]);
    }
    __syncthreads();

    for (int kt = 0; kt < 16; ++kt) {
        int cur = kt & 1;
        int t0 = sbase - 2; if (t0 < 0) t0 += 12;    // phys of wb(kt+1)

        // async stage next K/V tile + the 2 dxx entering window(kt+1)
        if (kt < 15) {
            const unsigned short* kg = kft + (kt + 1) * 4096;
            const unsigned short* vg = vft + (kt + 1) * 4096;
            unsigned short* dk = &lds_k[cur ^ 1][0];
            unsigned short* dv = &lds_v[cur ^ 1][0];
            g2l16(kg + off0 + lane * 8,        dk + off0);
            g2l16(kg + 2048 + off0 + lane * 8, dk + 2048 + off0);
            g2l16(vg + off0 + lane * 8,        dv + off0);
            g2l16(vg + 2048 + off0 + lane * 8, dv + 2048 + off0);
            int t1 = t0 + 1; if (t1 >= 12) t1 -= 12;
            int dx0 = (wb64 - 2) & 31;
            int dx1 = (wb64 - 1) & 31;
            g2l16(bGh + (dx0 * 4 + abb) * 256 + lane * 4,
                  &lds_bias[(t0 * 4 + abb) * 256]);
            g2l16(bGh + (dx1 * 4 + abb) * 256 + lane * 4,
                  &lds_bias[(t1 * 4 + abb) * 256]);
        }

        // phys bases for this wave's reads: rel = 2*wave + {0,1,2}
        int r0 = sbase + 2 * wave; if (r0 >= 12) r0 -= 12;
        int r1 = r0 + 1; if (r1 >= 12) r1 -= 12;
        int r2 = r0 + 2; if (r2 >= 12) r2 -= 12;
        const float* pb0 = &lds_bias[r0 * 1024 + lane * 4];
        const float* pb1 = &lds_bias[r1 * 1024 + lane * 4];
        const float* pb2 = &lds_bias[r2 * 1024 + lane * 4];

        // K,V fragments (shared across the 4 query tiles)
        bf16x8 kf2[4][2], vf2[4][2];
#pragma unroll
        for (int s = 0; s < 4; ++s)
#pragma unroll
            for (int c = 0; c < 2; ++c) {
                kf2[s][c] = ldfrag(&lds_k[cur][(s * 2 + c) * 512 + lane * 8]);
                vf2[s][c] = ldfrag(&lds_v[cur][(s * 2 + c) * 512 + lane * 8]);
            }

#pragma unroll
        for (int qt = 0; qt < 4; ++qt) {
            // s<2 (sh=0): rel = 2w+(qt>>1)+1 ; s>=2 (sh=1): rel = 2w+(qt>>1)
            const float* bhi = (qt & 2) ? pb2 : pb1;
            const float* blo = (qt & 2) ? pb1 : pb0;
            const int aoff = (qt & 1) * 512;         // a = tq&1 = qt&1
            floatx4 sv0 = *(const floatx4*)(bhi + aoff);
            floatx4 sv1 = *(const floatx4*)(bhi + aoff + 256);
            floatx4 sv2 = *(const floatx4*)(blo + aoff);
            floatx4 sv3 = *(const floatx4*)(blo + aoff + 256);

            __builtin_amdgcn_s_setprio(1);
            sv0 = __builtin_amdgcn_mfma_f32_16x16x32_bf16(kf2[0][0], aq[qt][0], sv0, 0, 0, 0);
            sv0 = __builtin_amdgcn_mfma_f32_16x16x32_bf16(kf2[0][1], aq[qt][1], sv0, 0, 0, 0);
            sv1 = __builtin_amdgcn_mfma_f32_16x16x32_bf16(kf2[1][0], aq[qt][0], sv1, 0, 0, 0);
            sv1 = __builtin_amdgcn_mfma_f32_16x16x32_bf16(kf2[1][1], aq[qt][1], sv1, 0, 0, 0);
            sv2 = __builtin_amdgcn_mfma_f32_16x16x32_bf16(kf2[2][0], aq[qt][0], sv2, 0, 0, 0);
            sv2 = __builtin_amdgcn_mfma_f32_16x16x32_bf16(kf2[2][1], aq[qt][1], sv2, 0, 0, 0);
            sv3 = __builtin_amdgcn_mfma_f32_16x16x32_bf16(kf2[3][0], aq[qt][0], sv3, 0, 0, 0);
            sv3 = __builtin_amdgcn_mfma_f32_16x16x32_bf16(kf2[3][1], aq[qt][1], sv3, 0, 0, 0);
            __builtin_amdgcn_s_setprio(0);

            uintx4 pu0, pu1;
            pu0[0] = pkbf_t(__builtin_amdgcn_exp2f(sv0[0]), __builtin_amdgcn_exp2f(sv0[1]));
            pu0[1] = pkbf_t(__builtin_amdgcn_exp2f(sv0[2]), __builtin_amdgcn_exp2f(sv0[3]));
            pu0[2] = pkbf_t(__builtin_amdgcn_exp2f(sv1[0]), __builtin_amdgcn_exp2f(sv1[1]));
            pu0[3] = pkbf_t(__builtin_amdgcn_exp2f(sv1[2]), __builtin_amdgcn_exp2f(sv1[3]));
            pu1[0] = pkbf_t(__builtin_amdgcn_exp2f(sv2[0]), __builtin_amdgcn_exp2f(sv2[1]));
            pu1[1] = pkbf_t(__builtin_amdgcn_exp2f(sv2[2]), __builtin_amdgcn_exp2f(sv2[3]));
            pu1[2] = pkbf_t(__builtin_amdgcn_exp2f(sv3[0]), __builtin_amdgcn_exp2f(sv3[1]));
            pu1[3] = pkbf_t(__builtin_amdgcn_exp2f(sv3[2]), __builtin_amdgcn_exp2f(sv3[3]));
            bf16x8 pf0 = __builtin_bit_cast(bf16x8, pu0);
            bf16x8 pf1 = __builtin_bit_cast(bf16x8, pu1);

            __builtin_amdgcn_s_setprio(1);
            acc_l[qt] = __builtin_amdgcn_mfma_f32_16x16x32_bf16(vone, pf0, acc_l[qt], 0, 0, 0);
            acc_l[qt] = __builtin_amdgcn_mfma_f32_16x16x32_bf16(vone, pf1, acc_l[qt], 0, 0, 0);
#pragma unroll
            for (int u = 0; u < 4; ++u) {
                o[qt][u] = __builtin_amdgcn_mfma_f32_16x16x32_bf16(vf2[u][0], pf0, o[qt][u], 0, 0, 0);
                o[qt][u] = __builtin_amdgcn_mfma_f32_16x16x32_bf16(vf2[u][1], pf1, o[qt][u], 0, 0, 0);
            }
            __builtin_amdgcn_s_setprio(0);
        }

        sbase = t0;
        wb64 -= 2;
        __syncthreads();   // drains staged global_load_lds for kt+1 too
    }

    // epilogue: O^T lane (q,n): query = i0+16qt+n, d = 16u+4q+r -> att2 A-frag
    for (int qt = 0; qt < 4; ++qt) {
        float inv = 1.0f / acc_l[qt][0];
        int pt = ti0 + qt;
        for (int u = 0; u < 4; ++u) {
            int kcA = 2 * h + (u >> 1);
            int q2 = 2 * (u & 1) + (q >> 1);
            uint2 pk;
            pk.x = pkbf(o[qt][u][0] * inv, o[qt][u][1] * inv);
            pk.y = pkbf(o[qt][u][2] * inv, o[qt][u][3] * inv);
            size_t addr = ((size_t)((b * 64 + pt) * 16 + kcA) * 512)
                          + (q2 * 16 + n) * 8 + 4 * (q & 1);
            *(uint2*)&att2[addr] = pk;
        }
    }
}

// ---------------- output projection + residual ----------------
__global__ __launch_bounds__(256, 4) void out_gemm(const unsigned short* __restrict__ att2,
                                                   const unsigned short* __restrict__ w0f,
                                                   const float* __restrict__ x,
                                                   float* __restrict__ out) {
    int b = blockIdx.x, ct = blockIdx.y, ptb = blockIdx.z;
    int tid = threadIdx.x, wave = tid >> 6, lane = tid & 63, q = lane >> 4, n = lane & 15;
    int pos0 = ptb * 64 + wave * 16;
    int c0 = ct * 64;
    int pt = ptb * 4 + wave;
    const unsigned short* abase = att2 + (size_t)(b * 64 + pt) * 16 * 512 + lane * 8;
    const unsigned short* wbase = w0f + (size_t)(c0 >> 4) * 16 * 512 + lane * 8;
    floatx4 acc[4];
    for (int s = 0; s < 4; ++s) acc[s] = (floatx4){0.f, 0.f, 0.f, 0.f};
    for (int g = 0; g < 4; ++g) {
        bf16x8 af[4], bfr[4][4];
        for (int k2 = 0; k2 < 4; ++k2) af[k2] = ldfrag(abase + (g * 4 + k2) * 512);
        for (int s = 0; s < 4; ++s)
            for (int k2 = 0; k2 < 4; ++k2)
                bfr[s][k2] = ldfrag(wbase + (s * 16 + g * 4 + k2) * 512);
        for (int k2 = 0; k2 < 4; ++k2)
            for (int s = 0; s < 4; ++s)
                acc[s] = __builtin_amdgcn_mfma_f32_16x16x32_bf16(af[k2], bfr[s][k2], acc[s], 0, 0, 0);
    }
    int p0q = pos0 + 4 * q;
    for (int s = 0; s < 4; ++s) {
        int c = c0 + 16 * s + n;
        size_t idx = ((size_t)b * CIN + c) * SEQ + p0q;
        floatx4 res = *(const floatx4*)&x[idx];
        floatx4 v = acc[s] + res;
        *(floatx4*)&out[idx] = v;
    }
}

// ---------------- launch ----------------
extern "C" void kernel_launch(void* const* d_in, const int* in_sizes, int n_in,
                              void* d_out, int out_size, void* d_ws, size_t ws_size,
                              hipStream_t stream) {
    const float* x  = (const float*)d_in[0];
    const float* Wq = (const float*)d_in[1];
    const float* Wk = (const float*)d_in[2];
    const float* Wv = (const float*)d_in[3];
    const float* R  = (const float*)d_in[4];
    const float* W0 = (const float*)d_in[5];
    float* out = (float*)d_out;

    char* ws = (char*)d_ws;
    size_t off = 0;
    unsigned short* Qt   = (unsigned short*)(ws + off); off += (size_t)NB * NH * SEQ * DKH * 2;
    unsigned short* Kf   = (unsigned short*)(ws + off); off += (size_t)NB * NH * SEQ * DKH * 2;
    unsigned short* Vf   = (unsigned short*)(ws + off); off += (size_t)NB * NH * SEQ * DKH * 2;
    unsigned short* att2 = (unsigned short*)(ws + off); off += (size_t)NB * SEQ * HDIM * 2;
    unsigned short* xt2  = (unsigned short*)(ws + off); off += (size_t)NB * SEQ * CIN * 2;
    unsigned short* w2   = (unsigned short*)(ws + off); off += (size_t)1536 * 128 * 2;
    unsigned short* w0f  = (unsigned short*)(ws + off); off += (size_t)128 * 512 * 2;
    float* biasG = (float*)(ws + off); off += (size_t)NH * 32 * 4 * 256 * 4;   // 1 MB
    (void)ws_size; (void)in_sizes; (void)n_in; (void)out_size;

    prep_all<<<2304, 256, 0, stream>>>(Wq, Wk, Wv, W0, R, x, w2, w0f, biasG, xt2);
    qkv_gemm<<<dim3(NB, 24, 16), 256, 0, stream>>>(xt2, w2, Qt, Kf, Vf);
    attn_kernel<<<NB * NH * 4, 256, 0, stream>>>(Qt, Kf, Vf, biasG, att2);
    out_gemm<<<dim3(NB, 2, 16), 256, 0, stream>>>(att2, w0f, x, out);
}